// Round 1
// baseline (121.285 us; speedup 1.0000x reference)
//
#include <hip/hip_runtime.h>
#include <hip/hip_bf16.h>
#include <stdint.h>

#define NROW 4096
#define DIM  512
#define BM   128
#define BN   128
#define BK   64

typedef __attribute__((ext_vector_type(8))) short  short8;   // 8 bf16 = 4 VGPRs
typedef __attribute__((ext_vector_type(4))) float  floatx4;  // MFMA 16x16 C/D

typedef const __attribute__((address_space(1))) void gvoid_t;
typedef __attribute__((address_space(3))) void       svoid_t;

__device__ __forceinline__ unsigned short f32_to_bf16_rne(float f) {
    unsigned u = __float_as_uint(f);
    u += 0x7FFFu + ((u >> 16) & 1u);
    return (unsigned short)(u >> 16);
}

// One block (64 threads) per row: fp32 row norm, bf16 conversion, out zeroing.
__global__ __launch_bounds__(64) void prep_kernel(
    const float* __restrict__ X, unsigned short* __restrict__ Xb,
    float* __restrict__ sq, float* __restrict__ out)
{
    const int row  = blockIdx.x;
    const int lane = threadIdx.x;
    const float4* xr = (const float4*)(X + (size_t)row * DIM);
    float4 v0 = xr[2 * lane];
    float4 v1 = xr[2 * lane + 1];
    float s = v0.x*v0.x + v0.y*v0.y + v0.z*v0.z + v0.w*v0.w
            + v1.x*v1.x + v1.y*v1.y + v1.z*v1.z + v1.w*v1.w;
    uint4 pk;
    pk.x = f32_to_bf16_rne(v0.x) | ((unsigned)f32_to_bf16_rne(v0.y) << 16);
    pk.y = f32_to_bf16_rne(v0.z) | ((unsigned)f32_to_bf16_rne(v0.w) << 16);
    pk.z = f32_to_bf16_rne(v1.x) | ((unsigned)f32_to_bf16_rne(v1.y) << 16);
    pk.w = f32_to_bf16_rne(v1.z) | ((unsigned)f32_to_bf16_rne(v1.w) << 16);
    *(uint4*)(Xb + (size_t)row * DIM + lane * 8) = pk;
    #pragma unroll
    for (int off = 32; off; off >>= 1) s += __shfl_xor(s, off);
    if (lane == 0) sq[row] = s;
    if (row == 0 && lane < 2) out[lane] = 0.0f;  // zero accumulators before main
}

// 128x128 tile of the Gram matrix per block; fused distance+mask reduction.
__global__ __launch_bounds__(256) void ccsa_kernel(
    const unsigned short* __restrict__ Xb, const float* __restrict__ sq,
    const int* __restrict__ ds, const int* __restrict__ y,
    const int* __restrict__ ncls, const int* __restrict__ ndom,
    float* __restrict__ out)
{
    __shared__ __align__(16) unsigned short As[BM * BK];  // [row][k], 64 bf16/row
    __shared__ __align__(16) unsigned short Bs[BN * BK];
    __shared__ float red[8];

    const int tid    = threadIdx.x;
    const int wave   = tid >> 6;
    const int lane   = tid & 63;
    const int warp_m = wave >> 1;       // 2x2 waves, each 64x64
    const int warp_n = wave & 1;
    const int bm0    = blockIdx.y * BM;
    const int bn0    = blockIdx.x * BN;

    floatx4 acc[4][4];
    #pragma unroll
    for (int a = 0; a < 4; ++a)
        #pragma unroll
        for (int b = 0; b < 4; ++b)
            acc[a][b] = (floatx4){0.f, 0.f, 0.f, 0.f};

    // staging geometry: 16B per lane; chunk c = issue*4+wave covers rows c*8..c*8+7
    const int l3       = lane >> 3;               // row within 8-row group
    const int c7       = lane & 7;                // dest 16B-chunk within 128B row
    const int srcchunk = c7 ^ l3;                 // XOR swizzle (row&7 == l3 here)
    const int m15      = lane & 15;
    const int quad     = lane >> 4;
    const int row7     = lane & 7;                // (row_local & 7) for frag reads

    for (int kt = 0; kt < DIM / BK; ++kt) {
        const size_t kbase = (size_t)kt * BK + srcchunk * 8;
        #pragma unroll
        for (int is = 0; is < 4; ++is) {
            const int c  = is * 4 + wave;
            const int rA = bm0 + c * 8 + l3;
            const int rB = bn0 + c * 8 + l3;
            __builtin_amdgcn_global_load_lds(
                (gvoid_t*)(Xb + (size_t)rA * DIM + kbase),
                (svoid_t*)(As + c * 512), 16, 0, 0);
            __builtin_amdgcn_global_load_lds(
                (gvoid_t*)(Xb + (size_t)rB * DIM + kbase),
                (svoid_t*)(Bs + c * 512), 16, 0, 0);
        }
        __syncthreads();

        #pragma unroll
        for (int kh = 0; kh < 2; ++kh) {
            short8 a[4], b[4];
            #pragma unroll
            for (int t = 0; t < 4; ++t) {
                const int rla   = warp_m * 64 + t * 16 + m15;
                const int rlb   = warp_n * 64 + t * 16 + m15;
                const int chunk = (kh * 4 + quad) ^ row7;   // un-swizzle
                a[t] = *(const short8*)(As + rla * 64 + chunk * 8);
                b[t] = *(const short8*)(Bs + rlb * 64 + chunk * 8);
            }
            #pragma unroll
            for (int tm = 0; tm < 4; ++tm)
                #pragma unroll
                for (int tn = 0; tn < 4; ++tn)
                    acc[tm][tn] = __builtin_amdgcn_mfma_f32_16x16x32_bf16(
                        a[tm], b[tn], acc[tm][tn], 0, 0, 0);
        }
        __syncthreads();
    }

    // Epilogue: C/D map col=lane&15, row=quad*4+reg (m89/m91 verified)
    float sqj[4]; int yj[4], dsj[4];
    #pragma unroll
    for (int tn = 0; tn < 4; ++tn) {
        const int j = bn0 + warp_n * 64 + tn * 16 + m15;
        sqj[tn] = sq[j]; yj[tn] = y[j]; dsj[tn] = ds[j];
    }
    float sa = 0.f, ss = 0.f;
    #pragma unroll
    for (int tm = 0; tm < 4; ++tm) {
        #pragma unroll
        for (int r = 0; r < 4; ++r) {
            const int i = bm0 + warp_m * 64 + tm * 16 + quad * 4 + r;
            const float sqi = sq[i];
            const int   yi  = y[i];
            const int   dsi = ds[i];
            #pragma unroll
            for (int tn = 0; tn < 4; ++tn) {
                if (dsi < dsj[tn]) {
                    const float d2   = sqi + sqj[tn] - 2.0f * acc[tm][tn][r];
                    const float dist = sqrtf(fmaxf(d2, 0.f));
                    if (yi == yj[tn])     sa += dist;
                    else if (yi < yj[tn]) ss += fmaxf(0.f, 1.f - dist);
                }
            }
        }
    }
    #pragma unroll
    for (int off = 32; off; off >>= 1) {
        sa += __shfl_xor(sa, off);
        ss += __shfl_xor(ss, off);
    }
    if (lane == 0) { red[wave] = sa; red[4 + wave] = ss; }
    __syncthreads();
    if (tid == 0) {
        const float tsa = red[0] + red[1] + red[2] + red[3];
        const float tss = red[4] + red[5] + red[6] + red[7];
        const int nc = *ncls, nd = *ndom;
        const float n_sa = (float)(nc * (nd * (nd - 1) / 2));
        const float n_s  = (float)((nc * (nc - 1) / 2) * (nd * (nd - 1) / 2));
        atomicAdd(out + 0, tsa * 0.5f / n_sa);
        atomicAdd(out + 1, tss * 0.5f / n_s);
    }
}

extern "C" void kernel_launch(void* const* d_in, const int* in_sizes, int n_in,
                              void* d_out, int out_size, void* d_ws, size_t ws_size,
                              hipStream_t stream) {
    (void)in_sizes; (void)n_in; (void)out_size; (void)ws_size;
    const float* X  = (const float*)d_in[0];
    const int*   ds = (const int*)d_in[1];
    const int*   y  = (const int*)d_in[2];
    const int*   nc = (const int*)d_in[3];
    const int*   nd = (const int*)d_in[4];
    float* out = (float*)d_out;

    unsigned short* Xb = (unsigned short*)d_ws;                       // 4 MB bf16 X
    float* sq = (float*)((char*)d_ws + (size_t)NROW * DIM * 2);       // 16 KB norms

    prep_kernel<<<NROW, 64, 0, stream>>>(X, Xb, sq, out);
    dim3 grid(NROW / BN, NROW / BM);
    ccsa_kernel<<<grid, 256, 0, stream>>>(Xb, sq, ds, y, nc, nd, out);
}

// Round 2
// 107.798 us; speedup vs baseline: 1.1251x; 1.1251x over previous
//
#include <hip/hip_runtime.h>
#include <hip/hip_bf16.h>
#include <stdint.h>

#define NROW 4096
#define DIM  512
#define BM   128
#define BN   128
#define BK   64
#define NKT  (DIM / BK)   // 8 k-tiles

typedef __attribute__((ext_vector_type(8))) short  short8;   // 8 bf16 = 4 VGPRs
typedef __attribute__((ext_vector_type(4))) float  floatx4;  // MFMA 16x16 C/D

typedef const __attribute__((address_space(1))) void gvoid_t;
typedef __attribute__((address_space(3))) void       svoid_t;

__device__ __forceinline__ unsigned short f32_to_bf16_rne(float f) {
    unsigned u = __float_as_uint(f);
    u += 0x7FFFu + ((u >> 16) & 1u);
    return (unsigned short)(u >> 16);
}

// 256 threads: wave w handles row blockIdx*4+w. fp32 row norm, bf16 convert,
// out zeroing (harness poisons d_out/d_ws with 0xAA before every launch).
__global__ __launch_bounds__(256) void prep_kernel(
    const float* __restrict__ X, unsigned short* __restrict__ Xb,
    float* __restrict__ sq, float* __restrict__ out)
{
    const int wave = threadIdx.x >> 6;
    const int lane = threadIdx.x & 63;
    const int row  = blockIdx.x * 4 + wave;
    const float4* xr = (const float4*)(X + (size_t)row * DIM);
    float4 v0 = xr[2 * lane];
    float4 v1 = xr[2 * lane + 1];
    float s = v0.x*v0.x + v0.y*v0.y + v0.z*v0.z + v0.w*v0.w
            + v1.x*v1.x + v1.y*v1.y + v1.z*v1.z + v1.w*v1.w;
    uint4 pk;
    pk.x = f32_to_bf16_rne(v0.x) | ((unsigned)f32_to_bf16_rne(v0.y) << 16);
    pk.y = f32_to_bf16_rne(v0.z) | ((unsigned)f32_to_bf16_rne(v0.w) << 16);
    pk.z = f32_to_bf16_rne(v1.x) | ((unsigned)f32_to_bf16_rne(v1.y) << 16);
    pk.w = f32_to_bf16_rne(v1.z) | ((unsigned)f32_to_bf16_rne(v1.w) << 16);
    *(uint4*)(Xb + (size_t)row * DIM + lane * 8) = pk;
    #pragma unroll
    for (int off = 32; off; off >>= 1) s += __shfl_xor(s, off);
    if (lane == 0) sq[row] = s;
    if (blockIdx.x == 0 && threadIdx.x < 2) out[threadIdx.x] = 0.0f;
}

// Upper-triangular 128x128 Gram tiles; single-barrier pipelined K-loop with
// double-buffered LDS; fused distance+mask reduction handling BOTH pair
// orientations for off-diagonal blocks (dist is symmetric).
__global__ __launch_bounds__(256) void ccsa_kernel(
    const unsigned short* __restrict__ Xb, const float* __restrict__ sq,
    const int* __restrict__ ds, const int* __restrict__ y,
    const int* __restrict__ ncls, const int* __restrict__ ndom,
    float* __restrict__ out)
{
    __shared__ __align__(16) unsigned short As[2][BM * BK];  // 2 x 16 KB
    __shared__ __align__(16) unsigned short Bs[2][BN * BK];  // 2 x 16 KB
    __shared__ float red[8];

    // triangular decode: block t -> (bi_t <= bj_t), 32*33/2 = 528 blocks
    const int t = blockIdx.x;
    int r = (int)((sqrtf(8.0f * (float)t + 1.0f) - 1.0f) * 0.5f);
    while ((r + 1) * (r + 2) / 2 <= t) ++r;
    while (r * (r + 1) / 2 > t) --r;
    const int bj_t = r;
    const int bi_t = t - r * (r + 1) / 2;
    const bool diag = (bi_t == bj_t);
    const int bm0 = bi_t * BM;
    const int bn0 = bj_t * BN;

    const int tid    = threadIdx.x;
    const int wave   = tid >> 6;
    const int lane   = tid & 63;
    const int warp_m = wave >> 1;       // 2x2 waves, each 64x64
    const int warp_n = wave & 1;

    floatx4 acc[4][4];
    #pragma unroll
    for (int a = 0; a < 4; ++a)
        #pragma unroll
        for (int b = 0; b < 4; ++b)
            acc[a][b] = (floatx4){0.f, 0.f, 0.f, 0.f};

    // staging geometry: 16B/lane; chunk c = is*4+wave covers rows c*8..c*8+7
    const int l3       = lane >> 3;               // row within 8-row group
    const int c7       = lane & 7;                // dest 16B-chunk in 128B row
    const int srcchunk = c7 ^ l3;                 // XOR swizzle (row&7 == l3)
    const int m15      = lane & 15;
    const int quad     = lane >> 4;
    const int row7     = lane & 7;                // row_local & 7 for frag reads

    #define STAGE(buf, kt)                                                    \
        do {                                                                  \
            const size_t kbase_ = (size_t)(kt) * BK + srcchunk * 8;           \
            _Pragma("unroll")                                                 \
            for (int is = 0; is < 4; ++is) {                                  \
                const int c  = is * 4 + wave;                                 \
                const int rA = bm0 + c * 8 + l3;                              \
                const int rB = bn0 + c * 8 + l3;                              \
                __builtin_amdgcn_global_load_lds(                             \
                    (gvoid_t*)(Xb + (size_t)rA * DIM + kbase_),               \
                    (svoid_t*)(&As[buf][c * 512]), 16, 0, 0);                 \
                __builtin_amdgcn_global_load_lds(                             \
                    (gvoid_t*)(Xb + (size_t)rB * DIM + kbase_),               \
                    (svoid_t*)(&Bs[buf][c * 512]), 16, 0, 0);                 \
            }                                                                 \
        } while (0)

    STAGE(0, 0);
    for (int kt = 0; kt < NKT; ++kt) {
        const int cur = kt & 1;
        // barrier drains the loads issued one compute-phase ago (and guards
        // LDS buffer reuse). Single barrier per iteration.
        __syncthreads();
        if (kt + 1 < NKT) STAGE(cur ^ 1, kt + 1);

        #pragma unroll
        for (int kh = 0; kh < 2; ++kh) {
            short8 a[4], b[4];
            #pragma unroll
            for (int tt = 0; tt < 4; ++tt) {
                const int rla   = warp_m * 64 + tt * 16 + m15;
                const int rlb   = warp_n * 64 + tt * 16 + m15;
                const int chunk = (kh * 4 + quad) ^ row7;   // un-swizzle
                a[tt] = *(const short8*)(&As[cur][rla * 64 + chunk * 8]);
                b[tt] = *(const short8*)(&Bs[cur][rlb * 64 + chunk * 8]);
            }
            #pragma unroll
            for (int tm = 0; tm < 4; ++tm)
                #pragma unroll
                for (int tn = 0; tn < 4; ++tn)
                    acc[tm][tn] = __builtin_amdgcn_mfma_f32_16x16x32_bf16(
                        a[tm], b[tn], acc[tm][tn], 0, 0, 0);
        }
    }
    #undef STAGE

    // Epilogue: C/D map col=lane&15, row=quad*4+reg (m89/m91 verified)
    float sqj[4]; int yj[4], dsj[4];
    #pragma unroll
    for (int tn = 0; tn < 4; ++tn) {
        const int j = bn0 + warp_n * 64 + tn * 16 + m15;
        sqj[tn] = sq[j]; yj[tn] = y[j]; dsj[tn] = ds[j];
    }
    float sa = 0.f, ss = 0.f;
    if (diag) {
        // both orientations live inside the tile: original one-sided mask
        #pragma unroll
        for (int tm = 0; tm < 4; ++tm) {
            #pragma unroll
            for (int rr = 0; rr < 4; ++rr) {
                const int i = bm0 + warp_m * 64 + tm * 16 + quad * 4 + rr;
                const float sqi = sq[i];
                const int   yi  = y[i];
                const int   dsi = ds[i];
                #pragma unroll
                for (int tn = 0; tn < 4; ++tn) {
                    if (dsi < dsj[tn]) {
                        const float d2   = sqi + sqj[tn] - 2.0f * acc[tm][tn][rr];
                        const float dist = sqrtf(fmaxf(d2, 0.f));
                        if (yi == yj[tn])     sa += dist;
                        else if (yi < yj[tn]) ss += fmaxf(0.f, 1.f - dist);
                    }
                }
            }
        }
    } else {
        // off-diagonal block: fold (i,j) and (j,i). Exactly one orientation
        // has d_lt true when ds_i != ds_j.
        #pragma unroll
        for (int tm = 0; tm < 4; ++tm) {
            #pragma unroll
            for (int rr = 0; rr < 4; ++rr) {
                const int i = bm0 + warp_m * 64 + tm * 16 + quad * 4 + rr;
                const float sqi = sq[i];
                const int   yi  = y[i];
                const int   dsi = ds[i];
                #pragma unroll
                for (int tn = 0; tn < 4; ++tn) {
                    if (dsi != dsj[tn]) {
                        const float d2   = sqi + sqj[tn] - 2.0f * acc[tm][tn][rr];
                        const float dist = sqrtf(fmaxf(d2, 0.f));
                        if (yi == yj[tn]) {
                            sa += dist;
                        } else {
                            const bool take = (dsi < dsj[tn]) ? (yi < yj[tn])
                                                              : (yj[tn] < yi);
                            if (take) ss += fmaxf(0.f, 1.f - dist);
                        }
                    }
                }
            }
        }
    }
    #pragma unroll
    for (int off = 32; off; off >>= 1) {
        sa += __shfl_xor(sa, off);
        ss += __shfl_xor(ss, off);
    }
    if (lane == 0) { red[wave] = sa; red[4 + wave] = ss; }
    __syncthreads();
    if (tid == 0) {
        const float tsa = red[0] + red[1] + red[2] + red[3];
        const float tss = red[4] + red[5] + red[6] + red[7];
        const int nc = *ncls, nd = *ndom;
        const float n_sa = (float)(nc * (nd * (nd - 1) / 2));
        const float n_s  = (float)((nc * (nc - 1) / 2) * (nd * (nd - 1) / 2));
        atomicAdd(out + 0, tsa * 0.5f / n_sa);
        atomicAdd(out + 1, tss * 0.5f / n_s);
    }
}

extern "C" void kernel_launch(void* const* d_in, const int* in_sizes, int n_in,
                              void* d_out, int out_size, void* d_ws, size_t ws_size,
                              hipStream_t stream) {
    (void)in_sizes; (void)n_in; (void)out_size; (void)ws_size;
    const float* X  = (const float*)d_in[0];
    const int*   ds = (const int*)d_in[1];
    const int*   y  = (const int*)d_in[2];
    const int*   nc = (const int*)d_in[3];
    const int*   nd = (const int*)d_in[4];
    float* out = (float*)d_out;

    unsigned short* Xb = (unsigned short*)d_ws;                       // 4 MB bf16 X
    float* sq = (float*)((char*)d_ws + (size_t)NROW * DIM * 2);       // 16 KB norms

    prep_kernel<<<NROW / 4, 256, 0, stream>>>(X, Xb, sq, out);
    const int ntiles = NROW / BM;                                     // 32
    const int nblocks = ntiles * (ntiles + 1) / 2;                    // 528
    ccsa_kernel<<<nblocks, 256, 0, stream>>>(Xb, sq, ds, y, nc, nd, out);
}